// Round 1
// baseline (195.968 us; speedup 1.0000x reference)
//
#include <hip/hip_runtime.h>

#define NQ 12
#define DIM (1 << NQ)       // 4096
#define NLAYERS 4
#define NTHREADS 256

__global__ __launch_bounds__(NTHREADS) void qsim_kernel(
    const float* __restrict__ x,     // [B][NQ]
    const float* __restrict__ w,     // [NLAYERS][NQ][3]
    float* __restrict__ out)         // [B][NQ]
{
    __shared__ float2 st[DIM];
    __shared__ float red[NTHREADS / 64][NQ];

    const int b   = blockIdx.x;
    const int tid = threadIdx.x;

    // ---- init |0...0> ----
    for (int k = tid; k < DIM; k += NTHREADS)
        st[k] = make_float2(k == 0 ? 1.f : 0.f, 0.f);
    __syncthreads();

    // ---- generic complex 1-qubit gate on `wire` ----
    auto apply1q = [&](int wire, float2 m00, float2 m01, float2 m10, float2 m11) {
        const int bb   = NQ - 1 - wire;      // bit position (wire 0 = MSB)
        const int mask = (1 << bb) - 1;
        #pragma unroll
        for (int it = 0; it < (DIM / 2) / NTHREADS; ++it) {
            int p  = tid + it * NTHREADS;
            int i0 = ((p & ~mask) << 1) | (p & mask);
            int i1 = i0 | (1 << bb);
            float2 a0 = st[i0], a1 = st[i1];
            float2 n0, n1;
            n0.x = m00.x * a0.x - m00.y * a0.y + m01.x * a1.x - m01.y * a1.y;
            n0.y = m00.x * a0.y + m00.y * a0.x + m01.x * a1.y + m01.y * a1.x;
            n1.x = m10.x * a0.x - m10.y * a0.y + m11.x * a1.x - m11.y * a1.y;
            n1.y = m10.x * a0.y + m10.y * a0.x + m11.x * a1.y + m11.y * a1.x;
            st[i0] = n0;
            st[i1] = n1;
        }
        __syncthreads();
    };

    // ---- CNOT(c, t): swap amplitudes with (c=1,t=0) <-> (c=1,t=1) ----
    auto cnot = [&](int c, int t) {
        const int bc = NQ - 1 - c;
        const int bt = NQ - 1 - t;
        const int lo = bc < bt ? bc : bt;
        const int hi = bc < bt ? bt : bc;
        const int lom = (1 << lo) - 1;
        const int him = (1 << hi) - 1;
        #pragma unroll
        for (int it = 0; it < (DIM / 4) / NTHREADS; ++it) {
            int p = tid + it * NTHREADS;
            int i = ((p & ~lom) << 1) | (p & lom);   // insert 0 at lo
            i = ((i & ~him) << 1) | (i & him);       // insert 0 at hi
            i |= (1 << bc);                          // control bit = 1, target = 0
            int j = i | (1 << bt);
            float2 ti = st[i], tj = st[j];
            st[i] = tj;
            st[j] = ti;
        }
        __syncthreads();
    };

    const float PI = 3.14159265358979323846f;

    // ---- RY embedding layer (real matrices, batch-dependent) ----
    for (int wire = 0; wire < NQ; ++wire) {
        float half = 0.5f * PI * x[b * NQ + wire];
        float c = cosf(half), s = sinf(half);
        apply1q(wire, make_float2(c, 0.f), make_float2(-s, 0.f),
                      make_float2(s, 0.f), make_float2(c, 0.f));
    }
    // ---- CNOT ring r=1 ----
    for (int i = 0; i < NQ; ++i)
        cnot(i, (i + 1) % NQ);

    // ---- entangling layers ----
    for (int l = 0; l < NLAYERS; ++l) {
        for (int wire = 0; wire < NQ; ++wire) {
            float phi   = w[(l * NQ + wire) * 3 + 0];
            float theta = w[(l * NQ + wire) * 3 + 1];
            float omega = w[(l * NQ + wire) * 3 + 2];
            float ct = cosf(0.5f * theta), stt = sinf(0.5f * theta);
            float ap = 0.5f * (phi + omega), am = 0.5f * (phi - omega);
            float cap = cosf(ap), sap = sinf(ap);
            float cam = cosf(am), sam = sinf(am);
            // m00 = conj(ep)*c ; m01 = -em*s ; m10 = conj(em)*s ; m11 = ep*c
            float2 m00 = make_float2(cap * ct, -sap * ct);
            float2 m01 = make_float2(-cam * stt, -sam * stt);
            float2 m10 = make_float2(cam * stt, -sam * stt);
            float2 m11 = make_float2(cap * ct, sap * ct);
            apply1q(wire, m00, m01, m10, m11);
        }
        int r = l % (NQ - 1) + 1;
        for (int i = 0; i < NQ; ++i)
            cnot(i, (i + r) % NQ);
    }

    // ---- per-wire <Z>: out[b][q] = sum_k |a_k|^2 * (1 - 2*bit_q(k)) ----
    float acc[NQ];
    #pragma unroll
    for (int q = 0; q < NQ; ++q) acc[q] = 0.f;

    for (int k = tid; k < DIM; k += NTHREADS) {
        float2 a = st[k];
        float p = a.x * a.x + a.y * a.y;
        #pragma unroll
        for (int q = 0; q < NQ; ++q)
            acc[q] += ((k >> (NQ - 1 - q)) & 1) ? -p : p;
    }

    // wave-level reduce (wave = 64 lanes)
    #pragma unroll
    for (int q = 0; q < NQ; ++q) {
        float v = acc[q];
        #pragma unroll
        for (int off = 32; off > 0; off >>= 1)
            v += __shfl_down(v, off);
        acc[q] = v;
    }

    const int wave = tid >> 6;
    const int lane = tid & 63;
    if (lane == 0) {
        #pragma unroll
        for (int q = 0; q < NQ; ++q) red[wave][q] = acc[q];
    }
    __syncthreads();

    if (tid < NQ) {
        float s = 0.f;
        #pragma unroll
        for (int wv = 0; wv < NTHREADS / 64; ++wv) s += red[wv][tid];
        out[b * NQ + tid] = s;
    }
}

extern "C" void kernel_launch(void* const* d_in, const int* in_sizes, int n_in,
                              void* d_out, int out_size, void* d_ws, size_t ws_size,
                              hipStream_t stream) {
    const float* x = (const float*)d_in[0];   // [B][NQ] float32
    const float* w = (const float*)d_in[1];   // [NLAYERS][NQ][3] float32
    float* out = (float*)d_out;               // [B][NQ] float32
    int batch = in_sizes[0] / NQ;
    qsim_kernel<<<batch, NTHREADS, 0, stream>>>(x, w, out);
}

// Round 2
// 144.934 us; speedup vs baseline: 1.3521x; 1.3521x over previous
//
#include <hip/hip_runtime.h>

#define NQ 12
#define NLAYERS 4

typedef float2 c32;

__device__ __forceinline__ float shx(float v, int mask) {
    return __shfl_xor(v, mask, 64);
}

// ---- 1q complex gate on a register bit RB (wires 6..11) ----
template<int RB>
__device__ __forceinline__ void gate_reg(c32 (&st)[64], c32 m00, c32 m01, c32 m10, c32 m11) {
    #pragma unroll
    for (int r = 0; r < 64; ++r) if (!(r & (1 << RB))) {
        const int r1 = r | (1 << RB);
        c32 a0 = st[r], a1 = st[r1];
        st[r].x  = m00.x*a0.x - m00.y*a0.y + m01.x*a1.x - m01.y*a1.y;
        st[r].y  = m00.x*a0.y + m00.y*a0.x + m01.x*a1.y + m01.y*a1.x;
        st[r1].x = m10.x*a0.x - m10.y*a0.y + m11.x*a1.x - m11.y*a1.y;
        st[r1].y = m10.x*a0.y + m10.y*a0.x + m11.x*a1.y + m11.y*a1.x;
    }
}

// ---- 1q complex gate on a lane bit LB (wires 0..5) ----
template<int LB>
__device__ __forceinline__ void gate_lane(c32 (&st)[64], int lane, c32 m00, c32 m01, c32 m10, c32 m11) {
    const bool hi = (lane >> LB) & 1;
    c32 mS, mO;
    mS.x = hi ? m11.x : m00.x;  mS.y = hi ? m11.y : m00.y;
    mO.x = hi ? m10.x : m01.x;  mO.y = hi ? m10.y : m01.y;
    #pragma unroll
    for (int r = 0; r < 64; ++r) {
        c32 own = st[r];
        c32 oth;
        oth.x = shx(own.x, 1 << LB);
        oth.y = shx(own.y, 1 << LB);
        st[r].x = mS.x*own.x - mS.y*own.y + mO.x*oth.x - mO.y*oth.y;
        st[r].y = mS.x*own.y + mS.y*own.x + mO.x*oth.y + mO.y*oth.x;
    }
}

// ---- RY (real matrix [[c,-s],[s,c]]) specializations ----
template<int RB>
__device__ __forceinline__ void ry_reg(c32 (&st)[64], float c, float s) {
    #pragma unroll
    for (int r = 0; r < 64; ++r) if (!(r & (1 << RB))) {
        const int r1 = r | (1 << RB);
        c32 a0 = st[r], a1 = st[r1];
        st[r].x  = c*a0.x - s*a1.x;  st[r].y  = c*a0.y - s*a1.y;
        st[r1].x = s*a0.x + c*a1.x;  st[r1].y = s*a0.y + c*a1.y;
    }
}
template<int LB>
__device__ __forceinline__ void ry_lane(c32 (&st)[64], int lane, float c, float s) {
    const bool hi = (lane >> LB) & 1;
    const float mO = hi ? s : -s;   // bit0: new = c*own - s*oth ; bit1: new = c*own + s*oth
    #pragma unroll
    for (int r = 0; r < 64; ++r) {
        c32 own = st[r];
        c32 oth;
        oth.x = shx(own.x, 1 << LB);
        oth.y = shx(own.y, 1 << LB);
        st[r].x = c*own.x + mO*oth.x;
        st[r].y = c*own.y + mO*oth.y;
    }
}

// ---- wire dispatch: wire W<6 -> lane bit (5-W); W>=6 -> register bit (11-W) ----
template<int W>
__device__ __forceinline__ void rot_w(c32 (&st)[64], int lane, c32 m00, c32 m01, c32 m10, c32 m11) {
    if constexpr (W < 6) gate_lane<5 - W>(st, lane, m00, m01, m10, m11);
    else                 gate_reg<11 - W>(st, m00, m01, m10, m11);
}
template<int W>
__device__ __forceinline__ void ry_w(c32 (&st)[64], int lane, float c, float s) {
    if constexpr (W < 6) ry_lane<5 - W>(st, lane, c, s);
    else                 ry_reg<11 - W>(st, c, s);
}

// ---- CNOT ring: (i, (i+S)%12) for i = 0..11, in order ----
// wires 0..5 are lane bits (5-w), wires 6..11 are register bits (11-w).
template<int S>
__device__ __forceinline__ void ring(c32 (&st)[64], int lane) {
    // Case B (i = 0 .. 5-S): both wires in lane space -> compose into ONE lane
    // permutation. final[k] = state[M1(M2(...Mn(k)))] -> apply gates in reverse.
    int src = lane;
    #pragma unroll
    for (int i = 5 - S; i >= 0; --i)
        src ^= ((src >> (5 - i)) & 1) << (5 - (i + S));
    #pragma unroll
    for (int r = 0; r < 64; ++r) {
        st[r].x = __shfl(st[r].x, src, 64);
        st[r].y = __shfl(st[r].y, src, 64);
    }
    // Remaining CNOTs i = 6-S .. 11, in original order.
    #pragma unroll
    for (int i = 6 - S; i < 12; ++i) {
        const int c = i, t = (i + S) % 12;
        if (c < 6) {
            // Case C: control lane bit (5-c), target register bit (11-t)
            const int tb = 1 << (11 - t);
            const bool ctrl = (lane >> (5 - c)) & 1;
            #pragma unroll
            for (int r = 0; r < 64; ++r) if (!(r & tb)) {
                c32 a = st[r], bv = st[r | tb];
                st[r].x      = ctrl ? bv.x : a.x;   st[r].y      = ctrl ? bv.y : a.y;
                st[r | tb].x = ctrl ? a.x  : bv.x;  st[r | tb].y = ctrl ? a.y  : bv.y;
            }
        } else if (t >= 6) {
            // Case A: both register bits -> compile-time register swap
            const int cb = 1 << (11 - c), tb = 1 << (11 - t);
            #pragma unroll
            for (int r = 0; r < 64; ++r) if ((r & cb) && !(r & tb)) {
                c32 tmp = st[r]; st[r] = st[r | tb]; st[r | tb] = tmp;
            }
        } else {
            // Case D: control register bit (11-c), target lane bit (5-t)
            const int cb = 1 << (11 - c);
            const int tm = 1 << (5 - t);
            #pragma unroll
            for (int r = 0; r < 64; ++r) if (r & cb) {
                st[r].x = shx(st[r].x, tm);
                st[r].y = shx(st[r].y, tm);
            }
        }
    }
}

__global__ __launch_bounds__(64, 1) void qsim_kernel(
    const float* __restrict__ x,    // [B][NQ]
    const float* __restrict__ w3,   // [NLAYERS][NQ][3]
    float* __restrict__ out)        // [B][NQ]
{
    const int b    = blockIdx.x;
    const int lane = threadIdx.x;

    c32 st[64];
    #pragma unroll
    for (int r = 0; r < 64; ++r) { st[r].x = 0.f; st[r].y = 0.f; }
    if (lane == 0) st[0].x = 1.f;

    const float PI = 3.14159265358979323846f;

    // ---- RY embedding ----
    #define RYW(W) { float half = 0.5f * PI * x[b * NQ + W]; \
                     float cc = cosf(half), ss = sinf(half); \
                     ry_w<W>(st, lane, cc, ss); }
    RYW(0) RYW(1) RYW(2) RYW(3) RYW(4) RYW(5)
    RYW(6) RYW(7) RYW(8) RYW(9) RYW(10) RYW(11)
    #undef RYW

    ring<1>(st, lane);

    // ---- entangling layers ----
    #pragma unroll 1
    for (int l = 0; l < NLAYERS; ++l) {
        #define ROTW(W) { \
            float phi = w3[(l * NQ + W) * 3 + 0]; \
            float th  = w3[(l * NQ + W) * 3 + 1]; \
            float om  = w3[(l * NQ + W) * 3 + 2]; \
            float ct  = cosf(0.5f * th), stt = sinf(0.5f * th); \
            float ap  = 0.5f * (phi + om), am = 0.5f * (phi - om); \
            float cap = cosf(ap), sap = sinf(ap); \
            float cam = cosf(am), sam = sinf(am); \
            c32 m00 = make_float2( cap * ct, -sap * ct); \
            c32 m01 = make_float2(-cam * stt, -sam * stt); \
            c32 m10 = make_float2( cam * stt, -sam * stt); \
            c32 m11 = make_float2( cap * ct,  sap * ct); \
            rot_w<W>(st, lane, m00, m01, m10, m11); }
        ROTW(0) ROTW(1) ROTW(2) ROTW(3) ROTW(4) ROTW(5)
        ROTW(6) ROTW(7) ROTW(8) ROTW(9) ROTW(10) ROTW(11)
        #undef ROTW

        if      (l == 0) ring<1>(st, lane);
        else if (l == 1) ring<2>(st, lane);
        else if (l == 2) ring<3>(st, lane);
        else             ring<4>(st, lane);
    }

    // ---- per-wire <Z> ----
    float S = 0.f;
    float accR[6];
    #pragma unroll
    for (int i = 0; i < 6; ++i) accR[i] = 0.f;
    #pragma unroll
    for (int r = 0; r < 64; ++r) {
        float pr = st[r].x * st[r].x + st[r].y * st[r].y;
        S += pr;
        #pragma unroll
        for (int rb = 0; rb < 6; ++rb)
            accR[rb] += ((r >> rb) & 1) ? -pr : pr;
    }

    float v[12];
    #pragma unroll
    for (int wq = 0; wq < 12; ++wq) {
        float val;
        if (wq < 6) val = ((lane >> (5 - wq)) & 1) ? -S : S;  // lane-bit wires
        else        val = accR[11 - wq];                      // register-bit wires
        #pragma unroll
        for (int m = 32; m > 0; m >>= 1) val += shx(val, m);
        v[wq] = val;
    }
    if (lane == 0) {
        #pragma unroll
        for (int wq = 0; wq < 12; ++wq) out[b * NQ + wq] = v[wq];
    }
}

extern "C" void kernel_launch(void* const* d_in, const int* in_sizes, int n_in,
                              void* d_out, int out_size, void* d_ws, size_t ws_size,
                              hipStream_t stream) {
    const float* x  = (const float*)d_in[0];   // [B][NQ] float32
    const float* w3 = (const float*)d_in[1];   // [NLAYERS][NQ][3] float32
    float* out = (float*)d_out;                // [B][NQ] float32
    int batch = in_sizes[0] / NQ;
    qsim_kernel<<<batch, 64, 0, stream>>>(x, w3, out);
}

// Round 3
// 108.689 us; speedup vs baseline: 1.8030x; 1.3335x over previous
//
#include <hip/hip_runtime.h>

#define NQ 12
#define NLAYERS 4

typedef unsigned uint2v __attribute__((ext_vector_type(2)));

// ---- value from lane ^ (1<<LB); all 64 lanes active ----
template<int LB>
__device__ __forceinline__ float lx(float v) {
    if constexpr (LB == 0) {          // DPP quad_perm [1,0,3,2]
        return __uint_as_float((unsigned)__builtin_amdgcn_update_dpp(
            0, (int)__float_as_uint(v), 0xB1, 0xF, 0xF, true));
    } else if constexpr (LB == 1) {   // DPP quad_perm [2,3,0,1]
        return __uint_as_float((unsigned)__builtin_amdgcn_update_dpp(
            0, (int)__float_as_uint(v), 0x4E, 0xF, 0xF, true));
    } else if constexpr (LB == 2) {
        return __shfl_xor(v, 4, 64);
    } else if constexpr (LB == 3) {
        return __shfl_xor(v, 8, 64);
    } else if constexpr (LB == 4) {
#if __has_builtin(__builtin_amdgcn_permlane16_swap)
        uint2v r = __builtin_amdgcn_permlane16_swap(__float_as_uint(v), __float_as_uint(v), false, false);
        return __uint_as_float(r.x) + __uint_as_float(r.y) - v;  // lo+hi-own = partner
#else
        return __shfl_xor(v, 16, 64);
#endif
    } else {
#if __has_builtin(__builtin_amdgcn_permlane32_swap)
        uint2v r = __builtin_amdgcn_permlane32_swap(__float_as_uint(v), __float_as_uint(v), false, false);
        return __uint_as_float(r.x) + __uint_as_float(r.y) - v;
#else
        return __shfl_xor(v, 32, 64);
#endif
    }
}

__device__ __forceinline__ float2 c2fma(float2 mA, float2 a, float2 mB, float2 b) {
    float2 r;
    r.x = mA.x * a.x - mA.y * a.y + mB.x * b.x - mB.y * b.y;
    r.y = mA.x * a.y + mA.y * a.x + mB.x * b.y + mB.y * b.x;
    return r;
}

#define XIDX(W, R, L) (((W) * 16 + (R)) * 64 + (L))

// ================= Rot gates =================
template<int RB>
__device__ __forceinline__ void gate_reg(float2 (&st)[16], float2 m00, float2 m01, float2 m10, float2 m11) {
    #pragma unroll
    for (int r = 0; r < 16; ++r) if (!(r & (1 << RB))) {
        const int r1 = r | (1 << RB);
        float2 a0 = st[r], a1 = st[r1];
        st[r]  = c2fma(m00, a0, m01, a1);
        st[r1] = c2fma(m10, a0, m11, a1);
    }
}

template<int LB>
__device__ __forceinline__ void gate_lane(float2 (&st)[16], int lane, float2 m00, float2 m01, float2 m10, float2 m11) {
    const bool hi = (lane >> LB) & 1;
    float2 mS, mO;
    mS.x = hi ? m11.x : m00.x;  mS.y = hi ? m11.y : m00.y;
    mO.x = hi ? m10.x : m01.x;  mO.y = hi ? m10.y : m01.y;
    #pragma unroll
    for (int r = 0; r < 16; ++r) {
        float2 o;
        o.x = lx<LB>(st[r].x);
        o.y = lx<LB>(st[r].y);
        st[r] = c2fma(mS, st[r], mO, o);
    }
}

template<int WB>
__device__ __forceinline__ void gate_wave(float2 (&st)[16], int wv, int lane, float2* xch,
                                          float2 m00, float2 m01, float2 m10, float2 m11) {
    const bool hi = (wv >> WB) & 1;
    float2 mS, mO;
    mS.x = hi ? m11.x : m00.x;  mS.y = hi ? m11.y : m00.y;
    mO.x = hi ? m10.x : m01.x;  mO.y = hi ? m10.y : m01.y;
    #pragma unroll
    for (int r = 0; r < 16; ++r) xch[XIDX(wv, r, lane)] = st[r];
    __syncthreads();
    const int pw = wv ^ (1 << WB);
    #pragma unroll
    for (int r = 0; r < 16; ++r) {
        float2 o = xch[XIDX(pw, r, lane)];
        st[r] = c2fma(mS, st[r], mO, o);
    }
    __syncthreads();
}

template<int W>
__device__ __forceinline__ void rot_w(float2 (&st)[16], int wv, int lane, float2* xch,
                                      float2 m00, float2 m01, float2 m10, float2 m11) {
    if constexpr (W < 2)      gate_wave<1 - W>(st, wv, lane, xch, m00, m01, m10, m11);
    else if constexpr (W < 8) gate_lane<7 - W>(st, lane, m00, m01, m10, m11);
    else                      gate_reg<11 - W>(st, m00, m01, m10, m11);
}

// ================= RY gates (real [[c,-s],[s,c]]) =================
template<int RB>
__device__ __forceinline__ void ry_reg(float2 (&st)[16], float c, float s) {
    #pragma unroll
    for (int r = 0; r < 16; ++r) if (!(r & (1 << RB))) {
        const int r1 = r | (1 << RB);
        float2 a0 = st[r], a1 = st[r1];
        st[r]  = make_float2(c * a0.x - s * a1.x, c * a0.y - s * a1.y);
        st[r1] = make_float2(s * a0.x + c * a1.x, s * a0.y + c * a1.y);
    }
}
template<int LB>
__device__ __forceinline__ void ry_lane(float2 (&st)[16], int lane, float c, float s) {
    const bool hi = (lane >> LB) & 1;
    const float so = hi ? s : -s;
    #pragma unroll
    for (int r = 0; r < 16; ++r) {
        float ox = lx<LB>(st[r].x), oy = lx<LB>(st[r].y);
        st[r] = make_float2(c * st[r].x + so * ox, c * st[r].y + so * oy);
    }
}
template<int WB>
__device__ __forceinline__ void ry_wave(float2 (&st)[16], int wv, int lane, float2* xch, float c, float s) {
    const bool hi = (wv >> WB) & 1;
    const float so = hi ? s : -s;
    #pragma unroll
    for (int r = 0; r < 16; ++r) xch[XIDX(wv, r, lane)] = st[r];
    __syncthreads();
    const int pw = wv ^ (1 << WB);
    #pragma unroll
    for (int r = 0; r < 16; ++r) {
        float2 o = xch[XIDX(pw, r, lane)];
        st[r] = make_float2(c * st[r].x + so * o.x, c * st[r].y + so * o.y);
    }
    __syncthreads();
}
template<int W>
__device__ __forceinline__ void ry_w(float2 (&st)[16], int wv, int lane, float2* xch, float c, float s) {
    if constexpr (W < 2)      ry_wave<1 - W>(st, wv, lane, xch, c, s);
    else if constexpr (W < 8) ry_lane<7 - W>(st, lane, c, s);
    else                      ry_reg<11 - W>(st, c, s);
}

// ================= CNOT primitives =================
template<int LB, int TB>  // control lane bit, target reg bit
__device__ __forceinline__ void cnot_lr(float2 (&st)[16], int lane) {
    const bool ctl = (lane >> LB) & 1;
    #pragma unroll
    for (int r = 0; r < 16; ++r) if (!(r & (1 << TB))) {
        const int r1 = r | (1 << TB);
        float2 lo = st[r], hi = st[r1];
        st[r]  = make_float2(ctl ? hi.x : lo.x, ctl ? hi.y : lo.y);
        st[r1] = make_float2(ctl ? lo.x : hi.x, ctl ? lo.y : hi.y);
    }
}
template<int CB, int LB>  // control reg bit, target lane bit
__device__ __forceinline__ void cnot_rl(float2 (&st)[16]) {
    #pragma unroll
    for (int r = 0; r < 16; ++r) if (r & (1 << CB)) {
        st[r].x = lx<LB>(st[r].x);
        st[r].y = lx<LB>(st[r].y);
    }
}
template<int CB, int TB>  // both reg bits: free SSA swap
__device__ __forceinline__ void cnot_rr(float2 (&st)[16]) {
    #pragma unroll
    for (int r = 0; r < 16; ++r) if ((r & (1 << CB)) && !(r & (1 << TB))) {
        float2 t = st[r]; st[r] = st[r | (1 << TB)]; st[r | (1 << TB)] = t;
    }
}
template<int WB, int LB>  // control wave bit, target lane bit
__device__ __forceinline__ void cnot_wl(float2 (&st)[16], int wv) {
    if ((wv >> WB) & 1) {
        #pragma unroll
        for (int r = 0; r < 16; ++r) {
            st[r].x = lx<LB>(st[r].x);
            st[r].y = lx<LB>(st[r].y);
        }
    }
}

__device__ __forceinline__ void llperm(float2 (&st)[16], int src) {
    const int bp = src << 2;
    #pragma unroll
    for (int r = 0; r < 16; ++r) {
        st[r].x = __int_as_float(__builtin_amdgcn_ds_bpermute(bp, __float_as_int(st[r].x)));
        st[r].y = __int_as_float(__builtin_amdgcn_ds_bpermute(bp, __float_as_int(st[r].y)));
    }
}

// ================= rings =================
__device__ void ring1(float2 (&st)[16], int wv, int lane, float2* xch) {
    // (0,1) wave-wave
    #pragma unroll
    for (int r = 0; r < 16; ++r) xch[XIDX(wv, r, lane)] = st[r];
    __syncthreads();
    if ((wv >> 1) & 1) {
        #pragma unroll
        for (int r = 0; r < 16; ++r) st[r] = xch[XIDX(wv ^ 1, r, lane)];
    }
    __syncthreads();
    cnot_wl<0, 5>(st, wv);                       // (1,2)
    int src = lane;                              // (2,3)..(6,7) composed
    src ^= ((src >> 1) & 1) << 0;
    src ^= ((src >> 2) & 1) << 1;
    src ^= ((src >> 3) & 1) << 2;
    src ^= ((src >> 4) & 1) << 3;
    src ^= ((src >> 5) & 1) << 4;
    llperm(st, src);
    cnot_lr<0, 3>(st, lane);                     // (7,8)
    cnot_rr<3, 2>(st); cnot_rr<2, 1>(st); cnot_rr<1, 0>(st);  // (8,9)(9,10)(10,11)
    // (11,0): reg bit0 -> wave bit1
    #pragma unroll
    for (int r = 0; r < 16; ++r) if (r & 1) xch[XIDX(wv, r, lane)] = st[r];
    __syncthreads();
    #pragma unroll
    for (int r = 0; r < 16; ++r) if (r & 1) st[r] = xch[XIDX(wv ^ 2, r, lane)];
    __syncthreads();
}

__device__ void ring2(float2 (&st)[16], int wv, int lane, float2* xch) {
    cnot_wl<1, 5>(st, wv);                       // (0,2)
    cnot_wl<0, 4>(st, wv);                       // (1,3)
    int src = lane;                              // (2,4)..(5,7) composed
    src ^= ((src >> 2) & 1) << 0;
    src ^= ((src >> 3) & 1) << 1;
    src ^= ((src >> 4) & 1) << 2;
    src ^= ((src >> 5) & 1) << 3;
    llperm(st, src);
    cnot_lr<1, 3>(st, lane);                     // (6,8)
    cnot_lr<0, 2>(st, lane);                     // (7,9)
    cnot_rr<3, 1>(st);                           // (8,10)
    cnot_rr<2, 0>(st);                           // (9,11)
    // (10,0) rb1->wv^2 ; (11,1) rb0->wv^1  (disjoint wires: merge)
    #pragma unroll
    for (int r = 0; r < 16; ++r) if (r & 3) xch[XIDX(wv, r, lane)] = st[r];
    __syncthreads();
    #pragma unroll
    for (int r = 0; r < 16; ++r) {
        const int pm = (r & 2) | (r & 1);
        if (pm) st[r] = xch[XIDX(wv ^ pm, r, lane)];
    }
    __syncthreads();
}

__device__ void ring3(float2 (&st)[16], int wv, int lane, float2* xch) {
    cnot_wl<1, 4>(st, wv);                       // (0,3)
    cnot_wl<0, 3>(st, wv);                       // (1,4)
    int src = lane;                              // (2,5)(3,6)(4,7) composed
    src ^= ((src >> 3) & 1) << 0;
    src ^= ((src >> 4) & 1) << 1;
    src ^= ((src >> 5) & 1) << 2;
    llperm(st, src);
    cnot_lr<2, 3>(st, lane);                     // (5,8)
    cnot_lr<1, 2>(st, lane);                     // (6,9)
    cnot_lr<0, 1>(st, lane);                     // (7,10)
    cnot_rr<3, 0>(st);                           // (8,11)
    // (9,0) rb2->wv^2 ; (10,1) rb1->wv^1
    #pragma unroll
    for (int r = 0; r < 16; ++r) if (r & 6) xch[XIDX(wv, r, lane)] = st[r];
    __syncthreads();
    #pragma unroll
    for (int r = 0; r < 16; ++r) {
        const int pm = (((r >> 2) & 1) << 1) | ((r >> 1) & 1);
        if (pm) st[r] = xch[XIDX(wv ^ pm, r, lane)];
    }
    __syncthreads();
    cnot_rl<0, 5>(st);                           // (11,2)
}

__device__ void ring4(float2 (&st)[16], int wv, int lane, float2* xch) {
    cnot_wl<1, 3>(st, wv);                       // (0,4)
    cnot_wl<0, 2>(st, wv);                       // (1,5)
    int src = lane;                              // (2,6)(3,7) composed
    src ^= ((src >> 4) & 1) << 0;
    src ^= ((src >> 5) & 1) << 1;
    llperm(st, src);
    cnot_lr<3, 3>(st, lane);                     // (4,8)
    cnot_lr<2, 2>(st, lane);                     // (5,9)
    cnot_lr<1, 1>(st, lane);                     // (6,10)
    cnot_lr<0, 0>(st, lane);                     // (7,11)
    // (8,0) rb3->wv^2 ; (9,1) rb2->wv^1
    #pragma unroll
    for (int r = 0; r < 16; ++r) if (r & 12) xch[XIDX(wv, r, lane)] = st[r];
    __syncthreads();
    #pragma unroll
    for (int r = 0; r < 16; ++r) {
        const int pm = (((r >> 3) & 1) << 1) | ((r >> 2) & 1);
        if (pm) st[r] = xch[XIDX(wv ^ pm, r, lane)];
    }
    __syncthreads();
    cnot_rl<1, 5>(st);                           // (10,2)
    cnot_rl<0, 4>(st);                           // (11,3)
}

// ================= matrix precompute (batch-independent) =================
__global__ void prep_mats(const float* __restrict__ w3, float2* __restrict__ mats) {
    int t = threadIdx.x;
    if (t < NLAYERS * NQ) {
        float phi = w3[t * 3 + 0], th = w3[t * 3 + 1], om = w3[t * 3 + 2];
        float ct = cosf(0.5f * th), s = sinf(0.5f * th);
        float ap = 0.5f * (phi + om), am = 0.5f * (phi - om);
        float cap = cosf(ap), sap = sinf(ap);
        float cam = cosf(am), sam = sinf(am);
        mats[t * 4 + 0] = make_float2( cap * ct, -sap * ct);
        mats[t * 4 + 1] = make_float2(-cam * s,  -sam * s);
        mats[t * 4 + 2] = make_float2( cam * s,  -sam * s);
        mats[t * 4 + 3] = make_float2( cap * ct,  sap * ct);
    }
}

// ================= main kernel =================
__global__ __launch_bounds__(256, 4) void qsim_kernel(
    const float* __restrict__ x,        // [B][NQ]
    const float2* __restrict__ mats,    // [NLAYERS][NQ][4]
    float* __restrict__ out)            // [B][NQ]
{
    __shared__ float2 xch[4 * 16 * 64];  // 32 KB

    const int b    = blockIdx.x;
    const int tid  = threadIdx.x;
    const int wv   = tid >> 6;
    const int lane = tid & 63;

    float2 st[16];
    #pragma unroll
    for (int r = 0; r < 16; ++r) st[r] = make_float2(0.f, 0.f);
    if (tid == 0) st[0].x = 1.f;

    const float PI = 3.14159265358979323846f;

    // ---- RY embedding ----
    #define RYW(W) { float h = 0.5f * PI * x[b * NQ + W]; \
                     float ss, cc; __sincosf(h, &ss, &cc); \
                     ry_w<W>(st, wv, lane, xch, cc, ss); }
    RYW(0) RYW(1) RYW(2) RYW(3) RYW(4) RYW(5)
    RYW(6) RYW(7) RYW(8) RYW(9) RYW(10) RYW(11)
    #undef RYW

    ring1(st, wv, lane, xch);

    // ---- entangling layers ----
    #pragma unroll 1
    for (int l = 0; l < NLAYERS; ++l) {
        const float2* M = mats + l * (NQ * 4);
        #define ROTW(W) rot_w<W>(st, wv, lane, xch, M[W*4+0], M[W*4+1], M[W*4+2], M[W*4+3]);
        ROTW(0) ROTW(1) ROTW(2) ROTW(3) ROTW(4) ROTW(5)
        ROTW(6) ROTW(7) ROTW(8) ROTW(9) ROTW(10) ROTW(11)
        #undef ROTW
        if      (l == 0) ring1(st, wv, lane, xch);
        else if (l == 1) ring2(st, wv, lane, xch);
        else if (l == 2) ring3(st, wv, lane, xch);
        else             ring4(st, wv, lane, xch);
    }

    // ---- per-wire <Z> ----
    float S = 0.f;
    float accR[4] = {0.f, 0.f, 0.f, 0.f};
    #pragma unroll
    for (int r = 0; r < 16; ++r) {
        float pr = st[r].x * st[r].x + st[r].y * st[r].y;
        S += pr;
        #pragma unroll
        for (int rb = 0; rb < 4; ++rb)
            accR[rb] += ((r >> rb) & 1) ? -pr : pr;
    }

    float v[12];
    v[0] = ((wv >> 1) & 1) ? -S : S;
    v[1] = (wv & 1) ? -S : S;
    #pragma unroll
    for (int W = 2; W < 8; ++W)
        v[W] = ((lane >> (7 - W)) & 1) ? -S : S;
    #pragma unroll
    for (int W = 8; W < 12; ++W)
        v[W] = accR[11 - W];

    #pragma unroll
    for (int q = 0; q < 12; ++q) {
        v[q] += lx<5>(v[q]);
        v[q] += lx<4>(v[q]);
        v[q] += lx<3>(v[q]);
        v[q] += lx<2>(v[q]);
        v[q] += lx<1>(v[q]);
        v[q] += lx<0>(v[q]);
    }

    float* red = (float*)xch;
    if (lane == 0) {
        #pragma unroll
        for (int q = 0; q < 12; ++q) red[wv * 12 + q] = v[q];
    }
    __syncthreads();
    if (tid < 12)
        out[b * NQ + tid] = red[tid] + red[12 + tid] + red[24 + tid] + red[36 + tid];
}

extern "C" void kernel_launch(void* const* d_in, const int* in_sizes, int n_in,
                              void* d_out, int out_size, void* d_ws, size_t ws_size,
                              hipStream_t stream) {
    const float* x  = (const float*)d_in[0];   // [B][NQ] float32
    const float* w3 = (const float*)d_in[1];   // [NLAYERS][NQ][3] float32
    float* out = (float*)d_out;                // [B][NQ] float32
    float2* mats = (float2*)d_ws;              // 48 * 4 * 8 B = 1536 B
    int batch = in_sizes[0] / NQ;
    prep_mats<<<1, 64, 0, stream>>>(w3, mats);
    qsim_kernel<<<batch, 256, 0, stream>>>(x, mats, out);
}

// Round 5
// 89.942 us; speedup vs baseline: 2.1788x; 1.2084x over previous
//
#include <hip/hip_runtime.h>

#define NQ 12
#define NLAYERS 4

typedef float v2f __attribute__((ext_vector_type(2)));
typedef unsigned uint2v __attribute__((ext_vector_type(2)));

// ---- value from lane ^ (1<<LB); all 64 lanes active ----
template<int LB>
__device__ __forceinline__ float lx(float v) {
    if constexpr (LB == 0) {          // DPP quad_perm [1,0,3,2]
        return __uint_as_float((unsigned)__builtin_amdgcn_update_dpp(
            0, (int)__float_as_uint(v), 0xB1, 0xF, 0xF, true));
    } else if constexpr (LB == 1) {   // DPP quad_perm [2,3,0,1]
        return __uint_as_float((unsigned)__builtin_amdgcn_update_dpp(
            0, (int)__float_as_uint(v), 0x4E, 0xF, 0xF, true));
    } else if constexpr (LB == 2) {
        return __shfl_xor(v, 4, 64);
    } else if constexpr (LB == 3) {
        return __shfl_xor(v, 8, 64);
    } else if constexpr (LB == 4) {
#if __has_builtin(__builtin_amdgcn_permlane16_swap)
        uint2v r = __builtin_amdgcn_permlane16_swap(__float_as_uint(v), __float_as_uint(v), false, false);
        return __uint_as_float(r.x) + __uint_as_float(r.y) - v;  // lo+hi-own = partner
#else
        return __shfl_xor(v, 16, 64);
#endif
    } else {
#if __has_builtin(__builtin_amdgcn_permlane32_swap)
        uint2v r = __builtin_amdgcn_permlane32_swap(__float_as_uint(v), __float_as_uint(v), false, false);
        return __uint_as_float(r.x) + __uint_as_float(r.y) - v;
#else
        return __shfl_xor(v, 32, 64);
#endif
    }
}

template<int LB>
__device__ __forceinline__ v2f lxv(v2f a) {
    v2f r;
    r.x = lx<LB>(a.x);
    r.y = lx<LB>(a.y);
    return r;
}

__device__ __forceinline__ v2f swap2(v2f a) { return __builtin_shufflevector(a, a, 1, 0); }

#define XIDX(W, R, L) (((W) * 16 + (R)) * 64 + (L))

// M layout per wire: [m00xx,m00yy, m01xx,m01yy, m10xx,m10yy, m11xx,m11yy]
// where mxx = {m.x, m.x}, myy = {-m.y, m.y}; m*a = mxx*a + myy*swap2(a)

// ================= Rot gates =================
template<int RB>
__device__ __forceinline__ void gate_reg(v2f (&st)[16], const v2f* __restrict__ M) {
    const v2f m00xx = M[0], m00yy = M[1], m01xx = M[2], m01yy = M[3];
    const v2f m10xx = M[4], m10yy = M[5], m11xx = M[6], m11yy = M[7];
    #pragma unroll
    for (int r = 0; r < 16; ++r) if (!(r & (1 << RB))) {
        const int r1 = r | (1 << RB);
        v2f a0 = st[r], a1 = st[r1];
        st[r]  = m00xx * a0 + m00yy * swap2(a0) + m01xx * a1 + m01yy * swap2(a1);
        st[r1] = m10xx * a0 + m10yy * swap2(a0) + m11xx * a1 + m11yy * swap2(a1);
    }
}

template<int LB>
__device__ __forceinline__ void gate_lane(v2f (&st)[16], int lane, const v2f* __restrict__ M) {
    const bool hi = (lane >> LB) & 1;
    const v2f mSxx = hi ? M[6] : M[0], mSyy = hi ? M[7] : M[1];
    const v2f mOxx = hi ? M[4] : M[2], mOyy = hi ? M[5] : M[3];
    #pragma unroll
    for (int r = 0; r < 16; ++r) {
        v2f own = st[r];
        v2f oth = lxv<LB>(own);
        st[r] = mSxx * own + mSyy * swap2(own) + mOxx * oth + mOyy * swap2(oth);
    }
}

template<int WB>
__device__ __forceinline__ void gate_wave(v2f (&st)[16], int wv, int lane, v2f* xch,
                                          const v2f* __restrict__ M) {
    const bool hi = (wv >> WB) & 1;
    const v2f mSxx = hi ? M[6] : M[0], mSyy = hi ? M[7] : M[1];
    const v2f mOxx = hi ? M[4] : M[2], mOyy = hi ? M[5] : M[3];
    #pragma unroll
    for (int r = 0; r < 16; ++r) xch[XIDX(wv, r, lane)] = st[r];
    __syncthreads();
    const int pw = wv ^ (1 << WB);
    #pragma unroll
    for (int r = 0; r < 16; ++r) {
        v2f o = xch[XIDX(pw, r, lane)];
        st[r] = mSxx * st[r] + mSyy * swap2(st[r]) + mOxx * o + mOyy * swap2(o);
    }
    __syncthreads();
}

template<int W>
__device__ __forceinline__ void rot_w(v2f (&st)[16], int wv, int lane, v2f* xch,
                                      const v2f* __restrict__ M) {
    if constexpr (W < 2)      gate_wave<1 - W>(st, wv, lane, xch, M);
    else if constexpr (W < 8) gate_lane<7 - W>(st, lane, M);
    else                      gate_reg<11 - W>(st, M);
}

// ================= RY gates (real [[c,-s],[s,c]]) =================
template<int RB>
__device__ __forceinline__ void ry_reg(v2f (&st)[16], float c, float s) {
    const v2f cc = v2f{c, c}, sp = v2f{s, s}, sn = v2f{-s, -s};
    #pragma unroll
    for (int r = 0; r < 16; ++r) if (!(r & (1 << RB))) {
        const int r1 = r | (1 << RB);
        v2f a0 = st[r], a1 = st[r1];
        st[r]  = cc * a0 + sn * a1;
        st[r1] = sp * a0 + cc * a1;
    }
}
template<int LB>
__device__ __forceinline__ void ry_lane(v2f (&st)[16], int lane, float c, float s) {
    const bool hi = (lane >> LB) & 1;
    const float sof = hi ? s : -s;
    const v2f so = v2f{sof, sof};
    const v2f cc = v2f{c, c};
    #pragma unroll
    for (int r = 0; r < 16; ++r) {
        v2f oth = lxv<LB>(st[r]);
        st[r] = cc * st[r] + so * oth;
    }
}
template<int WB>
__device__ __forceinline__ void ry_wave(v2f (&st)[16], int wv, int lane, v2f* xch, float c, float s) {
    const bool hi = (wv >> WB) & 1;
    const float sof = hi ? s : -s;
    const v2f so = v2f{sof, sof};
    const v2f cc = v2f{c, c};
    #pragma unroll
    for (int r = 0; r < 16; ++r) xch[XIDX(wv, r, lane)] = st[r];
    __syncthreads();
    const int pw = wv ^ (1 << WB);
    #pragma unroll
    for (int r = 0; r < 16; ++r) {
        v2f o = xch[XIDX(pw, r, lane)];
        st[r] = cc * st[r] + so * o;
    }
    __syncthreads();
}
template<int W>
__device__ __forceinline__ void ry_w(v2f (&st)[16], int wv, int lane, v2f* xch, float c, float s) {
    if constexpr (W < 2)      ry_wave<1 - W>(st, wv, lane, xch, c, s);
    else if constexpr (W < 8) ry_lane<7 - W>(st, lane, c, s);
    else                      ry_reg<11 - W>(st, c, s);
}

// ================= CNOT primitives =================
template<int LB, int TB>  // control lane bit, target reg bit
__device__ __forceinline__ void cnot_lr(v2f (&st)[16], int lane) {
    const bool ctl = (lane >> LB) & 1;
    #pragma unroll
    for (int r = 0; r < 16; ++r) if (!(r & (1 << TB))) {
        const int r1 = r | (1 << TB);
        v2f lo = st[r], hi = st[r1];
        st[r]  = ctl ? hi : lo;
        st[r1] = ctl ? lo : hi;
    }
}
template<int CB, int LB>  // control reg bit, target lane bit
__device__ __forceinline__ void cnot_rl(v2f (&st)[16]) {
    #pragma unroll
    for (int r = 0; r < 16; ++r) if (r & (1 << CB)) st[r] = lxv<LB>(st[r]);
}
template<int CB, int TB>  // both reg bits: free SSA swap
__device__ __forceinline__ void cnot_rr(v2f (&st)[16]) {
    #pragma unroll
    for (int r = 0; r < 16; ++r) if ((r & (1 << CB)) && !(r & (1 << TB))) {
        v2f t = st[r]; st[r] = st[r | (1 << TB)]; st[r | (1 << TB)] = t;
    }
}
template<int WB, int LB>  // control wave bit, target lane bit
__device__ __forceinline__ void cnot_wl(v2f (&st)[16], int wv) {
    if ((wv >> WB) & 1) {
        #pragma unroll
        for (int r = 0; r < 16; ++r) st[r] = lxv<LB>(st[r]);
    }
}

__device__ __forceinline__ void llperm(v2f (&st)[16], int src) {
    const int bp = src << 2;
    #pragma unroll
    for (int r = 0; r < 16; ++r) {
        st[r].x = __int_as_float(__builtin_amdgcn_ds_bpermute(bp, __float_as_int(st[r].x)));
        st[r].y = __int_as_float(__builtin_amdgcn_ds_bpermute(bp, __float_as_int(st[r].y)));
    }
}

// ================= rings =================
__device__ void ring1(v2f (&st)[16], int wv, int lane, v2f* xch) {
    #pragma unroll
    for (int r = 0; r < 16; ++r) xch[XIDX(wv, r, lane)] = st[r];      // (0,1)
    __syncthreads();
    if ((wv >> 1) & 1) {
        #pragma unroll
        for (int r = 0; r < 16; ++r) st[r] = xch[XIDX(wv ^ 1, r, lane)];
    }
    __syncthreads();
    cnot_wl<0, 5>(st, wv);                       // (1,2)
    int src = lane;                              // (2,3)..(6,7)
    src ^= ((src >> 1) & 1) << 0;
    src ^= ((src >> 2) & 1) << 1;
    src ^= ((src >> 3) & 1) << 2;
    src ^= ((src >> 4) & 1) << 3;
    src ^= ((src >> 5) & 1) << 4;
    llperm(st, src);
    cnot_lr<0, 3>(st, lane);                     // (7,8)
    cnot_rr<3, 2>(st); cnot_rr<2, 1>(st); cnot_rr<1, 0>(st);  // (8,9)(9,10)(10,11)
    #pragma unroll
    for (int r = 0; r < 16; ++r) if (r & 1) xch[XIDX(wv, r, lane)] = st[r];  // (11,0)
    __syncthreads();
    #pragma unroll
    for (int r = 0; r < 16; ++r) if (r & 1) st[r] = xch[XIDX(wv ^ 2, r, lane)];
    __syncthreads();
}

__device__ void ring2(v2f (&st)[16], int wv, int lane, v2f* xch) {
    cnot_wl<1, 5>(st, wv);                       // (0,2)
    cnot_wl<0, 4>(st, wv);                       // (1,3)
    int src = lane;                              // (2,4)..(5,7)
    src ^= ((src >> 2) & 1) << 0;
    src ^= ((src >> 3) & 1) << 1;
    src ^= ((src >> 4) & 1) << 2;
    src ^= ((src >> 5) & 1) << 3;
    llperm(st, src);
    cnot_lr<1, 3>(st, lane);                     // (6,8)
    cnot_lr<0, 2>(st, lane);                     // (7,9)
    cnot_rr<3, 1>(st);                           // (8,10)
    cnot_rr<2, 0>(st);                           // (9,11)
    #pragma unroll
    for (int r = 0; r < 16; ++r) if (r & 3) xch[XIDX(wv, r, lane)] = st[r];  // (10,0)(11,1)
    __syncthreads();
    #pragma unroll
    for (int r = 0; r < 16; ++r) {
        const int pm = (r & 2) | (r & 1);
        if (pm) st[r] = xch[XIDX(wv ^ pm, r, lane)];
    }
    __syncthreads();
}

__device__ void ring3(v2f (&st)[16], int wv, int lane, v2f* xch) {
    cnot_wl<1, 4>(st, wv);                       // (0,3)
    cnot_wl<0, 3>(st, wv);                       // (1,4)
    int src = lane;                              // (2,5)(3,6)(4,7)
    src ^= ((src >> 3) & 1) << 0;
    src ^= ((src >> 4) & 1) << 1;
    src ^= ((src >> 5) & 1) << 2;
    llperm(st, src);
    cnot_lr<2, 3>(st, lane);                     // (5,8)
    cnot_lr<1, 2>(st, lane);                     // (6,9)
    cnot_lr<0, 1>(st, lane);                     // (7,10)
    cnot_rr<3, 0>(st);                           // (8,11)
    #pragma unroll
    for (int r = 0; r < 16; ++r) if (r & 6) xch[XIDX(wv, r, lane)] = st[r];  // (9,0)(10,1)
    __syncthreads();
    #pragma unroll
    for (int r = 0; r < 16; ++r) {
        const int pm = (((r >> 2) & 1) << 1) | ((r >> 1) & 1);
        if (pm) st[r] = xch[XIDX(wv ^ pm, r, lane)];
    }
    __syncthreads();
    cnot_rl<0, 5>(st);                           // (11,2)
}

__device__ void ring4(v2f (&st)[16], int wv, int lane, v2f* xch) {
    cnot_wl<1, 3>(st, wv);                       // (0,4)
    cnot_wl<0, 2>(st, wv);                       // (1,5)
    int src = lane;                              // (2,6)(3,7)
    src ^= ((src >> 4) & 1) << 0;
    src ^= ((src >> 5) & 1) << 1;
    llperm(st, src);
    cnot_lr<3, 3>(st, lane);                     // (4,8)
    cnot_lr<2, 2>(st, lane);                     // (5,9)
    cnot_lr<1, 1>(st, lane);                     // (6,10)
    cnot_lr<0, 0>(st, lane);                     // (7,11)
    #pragma unroll
    for (int r = 0; r < 16; ++r) if (r & 12) xch[XIDX(wv, r, lane)] = st[r]; // (8,0)(9,1)
    __syncthreads();
    #pragma unroll
    for (int r = 0; r < 16; ++r) {
        const int pm = (((r >> 3) & 1) << 1) | ((r >> 2) & 1);
        if (pm) st[r] = xch[XIDX(wv ^ pm, r, lane)];
    }
    __syncthreads();
    cnot_rl<1, 5>(st);                           // (10,2)
    cnot_rl<0, 4>(st);                           // (11,3)
}

// ================= matrix precompute (batch-independent, packed) =================
__global__ void prep_mats(const float* __restrict__ w3, v2f* __restrict__ mats) {
    int t = threadIdx.x;
    if (t < NLAYERS * NQ) {
        float phi = w3[t * 3 + 0], th = w3[t * 3 + 1], om = w3[t * 3 + 2];
        float ct = cosf(0.5f * th), s = sinf(0.5f * th);
        float ap = 0.5f * (phi + om), am = 0.5f * (phi - om);
        float cap = cosf(ap), sap = sinf(ap);
        float cam = cosf(am), sam = sinf(am);
        // m00 = ( cap*ct, -sap*ct)   m01 = (-cam*s, -sam*s)
        // m10 = ( cam*s,  -sam*s)    m11 = ( cap*ct,  sap*ct)
        float2 m00 = make_float2( cap * ct, -sap * ct);
        float2 m01 = make_float2(-cam * s,  -sam * s);
        float2 m10 = make_float2( cam * s,  -sam * s);
        float2 m11 = make_float2( cap * ct,  sap * ct);
        v2f* M = mats + t * 8;
        M[0] = v2f{m00.x, m00.x};  M[1] = v2f{-m00.y, m00.y};
        M[2] = v2f{m01.x, m01.x};  M[3] = v2f{-m01.y, m01.y};
        M[4] = v2f{m10.x, m10.x};  M[5] = v2f{-m10.y, m10.y};
        M[6] = v2f{m11.x, m11.x};  M[7] = v2f{-m11.y, m11.y};
    }
}

__device__ __forceinline__ float wsum(float v) {
    v += lx<5>(v); v += lx<4>(v); v += lx<3>(v);
    v += lx<2>(v); v += lx<1>(v); v += lx<0>(v);
    return v;
}

// ================= main kernel =================
__global__ __launch_bounds__(256)
__attribute__((amdgpu_waves_per_eu(2, 4)))
void qsim_kernel(
    const float* __restrict__ x,       // [B][NQ]
    const v2f* __restrict__ mats,      // [NLAYERS][NQ][8] packed
    float* __restrict__ out)           // [B][NQ]
{
    __shared__ v2f xch[4 * 16 * 64];   // 32 KB

    const int b    = blockIdx.x;
    const int tid  = threadIdx.x;
    const int wv   = tid >> 6;
    const int lane = tid & 63;

    v2f st[16];
    #pragma unroll
    for (int r = 0; r < 16; ++r) st[r] = v2f{0.f, 0.f};
    if (tid == 0) st[0].x = 1.f;

    const float PI = 3.14159265358979323846f;

    // ---- RY embedding ----
    #define RYW(W) { float h = 0.5f * PI * x[b * NQ + W]; \
                     float ss, cc; __sincosf(h, &ss, &cc); \
                     ry_w<W>(st, wv, lane, xch, cc, ss); }
    RYW(0) RYW(1) RYW(2) RYW(3) RYW(4) RYW(5)
    RYW(6) RYW(7) RYW(8) RYW(9) RYW(10) RYW(11)
    #undef RYW

    ring1(st, wv, lane, xch);

    // ---- entangling layers ----
    #pragma unroll 1
    for (int l = 0; l < NLAYERS; ++l) {
        const v2f* M = mats + l * (NQ * 8);
        #define ROTW(W) rot_w<W>(st, wv, lane, xch, M + W * 8);
        ROTW(0) ROTW(1) ROTW(2) ROTW(3) ROTW(4) ROTW(5)
        ROTW(6) ROTW(7) ROTW(8) ROTW(9) ROTW(10) ROTW(11)
        #undef ROTW
        if      (l == 0) ring1(st, wv, lane, xch);
        else if (l == 1) ring2(st, wv, lane, xch);
        else if (l == 2) ring3(st, wv, lane, xch);
        else             ring4(st, wv, lane, xch);
    }

    // ---- per-wire <Z>, one wire at a time (low live-register pressure) ----
    float S = 0.f;
    float aR[4] = {0.f, 0.f, 0.f, 0.f};
    #pragma unroll
    for (int r = 0; r < 16; ++r) {
        v2f sq = st[r] * st[r];
        float pr = sq.x + sq.y;
        S += pr;
        #pragma unroll
        for (int rb = 0; rb < 4; ++rb)
            aR[rb] += ((r >> rb) & 1) ? -pr : pr;
    }

    float* red = (float*)xch;

    // wave wires 0,1: one shared butterfly, wave-dependent sign at write
    {
        float T = wsum(S);
        if (lane == 0) {
            red[wv * 12 + 0] = ((wv >> 1) & 1) ? -T : T;
            red[wv * 12 + 1] = (wv & 1) ? -T : T;
        }
    }
    // lane wires 2..7 (wire W -> lane bit 7-W)
    #pragma unroll
    for (int W = 2; W < 8; ++W) {
        float v0 = ((lane >> (7 - W)) & 1) ? -S : S;
        v0 = wsum(v0);
        if (lane == 0) red[wv * 12 + W] = v0;
    }
    // reg wires 8..11
    #pragma unroll
    for (int W = 8; W < 12; ++W) {
        float v0 = wsum(aR[11 - W]);
        if (lane == 0) red[wv * 12 + W] = v0;
    }
    __syncthreads();
    if (tid < 12)
        out[b * NQ + tid] = red[tid] + red[12 + tid] + red[24 + tid] + red[36 + tid];
}

extern "C" void kernel_launch(void* const* d_in, const int* in_sizes, int n_in,
                              void* d_out, int out_size, void* d_ws, size_t ws_size,
                              hipStream_t stream) {
    const float* x  = (const float*)d_in[0];   // [B][NQ] float32
    const float* w3 = (const float*)d_in[1];   // [NLAYERS][NQ][3] float32
    float* out = (float*)d_out;                // [B][NQ] float32
    v2f* mats = (v2f*)d_ws;                    // 48 * 8 * 8 B = 3 KB
    int batch = in_sizes[0] / NQ;
    prep_mats<<<1, 64, 0, stream>>>(w3, mats);
    qsim_kernel<<<batch, 256, 0, stream>>>(x, mats, out);
}

// Round 7
// 77.466 us; speedup vs baseline: 2.5297x; 1.1610x over previous
//
#include <hip/hip_runtime.h>

#define NQ 12
#define NLAYERS 4

typedef float v2f __attribute__((ext_vector_type(2)));
typedef unsigned uint2v __attribute__((ext_vector_type(2)));

// ---- value from lane ^ (1<<LB); all 64 lanes active ----
template<int LB>
__device__ __forceinline__ float lx(float v) {
    if constexpr (LB == 0) {          // DPP quad_perm [1,0,3,2]
        return __uint_as_float((unsigned)__builtin_amdgcn_update_dpp(
            0, (int)__float_as_uint(v), 0xB1, 0xF, 0xF, true));
    } else if constexpr (LB == 1) {   // DPP quad_perm [2,3,0,1]
        return __uint_as_float((unsigned)__builtin_amdgcn_update_dpp(
            0, (int)__float_as_uint(v), 0x4E, 0xF, 0xF, true));
    } else if constexpr (LB == 2) {
        return __shfl_xor(v, 4, 64);
    } else if constexpr (LB == 3) {
        return __shfl_xor(v, 8, 64);
    } else if constexpr (LB == 4) {
#if __has_builtin(__builtin_amdgcn_permlane16_swap)
        uint2v r = __builtin_amdgcn_permlane16_swap(__float_as_uint(v), __float_as_uint(v), false, false);
        return __uint_as_float(r.x) + __uint_as_float(r.y) - v;  // lo+hi-own = partner
#else
        return __shfl_xor(v, 16, 64);
#endif
    } else {
#if __has_builtin(__builtin_amdgcn_permlane32_swap)
        uint2v r = __builtin_amdgcn_permlane32_swap(__float_as_uint(v), __float_as_uint(v), false, false);
        return __uint_as_float(r.x) + __uint_as_float(r.y) - v;
#else
        return __shfl_xor(v, 32, 64);
#endif
    }
}

template<int LB>
__device__ __forceinline__ v2f lxv(v2f a) {
    v2f r;
    r.x = lx<LB>(a.x);
    r.y = lx<LB>(a.y);
    return r;
}

__device__ __forceinline__ v2f swap2(v2f a) { return __builtin_shufflevector(a, a, 1, 0); }

// ======== composed ring permutation: source index for CNOT ring (i,(i+S)%12), i=0..11 ========
// state'[k] = state[C0(C1(...C11(k)))]  (wire w <-> bit 11-w); XOR-linear in k.
template<int S>
__host__ __device__ constexpr int ringsrc_c(int k) {
    int s = k;
    for (int i = 11; i >= 0; --i) {
        const int pc = 11 - i;
        const int pt = 11 - ((i + S) % 12);
        s ^= ((s >> pc) & 1) << pt;
    }
    return s;
}

struct LUT16 { int v[16]; };

// per-register phys-space source offsets (compile-time)
template<int S>
__host__ __device__ constexpr LUT16 make_pr() {
    LUT16 a{};
    for (int r = 0; r < 16; ++r) {
        int c = ringsrc_c<S>(r);
        a.v[r] = c ^ ((c >> 4) & 15);
    }
    return a;
}

// LDS swizzle: phys(k) = k ^ ((k>>4)&15)  (XOR low lane bits into reg bits) — linear.
// Applied on BOTH write and read sides.

// ring as ONE swizzled LDS write/read round trip
template<int S>
__device__ __forceinline__ void ring_trip(v2f (&st)[16], int wbase, int lsw, v2f* xch) {
    #pragma unroll
    for (int r = 0; r < 16; ++r) xch[wbase | (r ^ lsw)] = st[r];
    __syncthreads();
    const int sb = ringsrc_c<S>(wbase);          // runtime part (linear)
    const int pb = sb ^ ((sb >> 4) & 15);        // phys of base
    constexpr LUT16 PR = make_pr<S>();
    #pragma unroll
    for (int r = 0; r < 16; ++r) st[r] = xch[pb ^ PR.v[r]];
    __syncthreads();
}

// M layout per wire: [m00xx,m00yy, m01xx,m01yy, m10xx,m10yy, m11xx,m11yy]
// where mxx = {m.x, m.x}, myy = {-m.y, m.y}; m*a = mxx*a + myy*swap2(a)

// ================= Rot gates =================
template<int RB>
__device__ __forceinline__ void gate_reg(v2f (&st)[16], const v2f* __restrict__ M) {
    const v2f m00xx = M[0], m00yy = M[1], m01xx = M[2], m01yy = M[3];
    const v2f m10xx = M[4], m10yy = M[5], m11xx = M[6], m11yy = M[7];
    #pragma unroll
    for (int r = 0; r < 16; ++r) if (!(r & (1 << RB))) {
        const int r1 = r | (1 << RB);
        v2f a0 = st[r], a1 = st[r1];
        st[r]  = m00xx * a0 + m00yy * swap2(a0) + m01xx * a1 + m01yy * swap2(a1);
        st[r1] = m10xx * a0 + m10yy * swap2(a0) + m11xx * a1 + m11yy * swap2(a1);
    }
}

template<int LB>
__device__ __forceinline__ void gate_lane(v2f (&st)[16], int lane, const v2f* __restrict__ M) {
    const bool hi = (lane >> LB) & 1;
    const v2f mSxx = hi ? M[6] : M[0], mSyy = hi ? M[7] : M[1];
    const v2f mOxx = hi ? M[4] : M[2], mOyy = hi ? M[5] : M[3];
    #pragma unroll
    for (int r = 0; r < 16; ++r) {
        v2f own = st[r];
        v2f oth = lxv<LB>(own);
        st[r] = mSxx * own + mSyy * swap2(own) + mOxx * oth + mOyy * swap2(oth);
    }
}

template<int WB>
__device__ __forceinline__ void gate_wave(v2f (&st)[16], int wbase, int lsw, v2f* xch,
                                          int wv, const v2f* __restrict__ M) {
    const bool hi = (wv >> WB) & 1;
    const v2f mSxx = hi ? M[6] : M[0], mSyy = hi ? M[7] : M[1];
    const v2f mOxx = hi ? M[4] : M[2], mOyy = hi ? M[5] : M[3];
    #pragma unroll
    for (int r = 0; r < 16; ++r) xch[wbase | (r ^ lsw)] = st[r];
    __syncthreads();
    const int pmask = 1 << (10 + WB);
    #pragma unroll
    for (int r = 0; r < 16; ++r) {
        v2f o = xch[(wbase ^ pmask) | (r ^ lsw)];
        st[r] = mSxx * st[r] + mSyy * swap2(st[r]) + mOxx * o + mOyy * swap2(o);
    }
    __syncthreads();
}

template<int W>
__device__ __forceinline__ void rot_w(v2f (&st)[16], int wv, int lane, int wbase, int lsw,
                                      v2f* xch, const v2f* __restrict__ M) {
    if constexpr (W < 2)      gate_wave<1 - W>(st, wbase, lsw, xch, wv, M);
    else if constexpr (W < 8) gate_lane<7 - W>(st, lane, M);
    else                      gate_reg<11 - W>(st, M);
}

// ================= matrix precompute (batch-independent, packed) =================
__global__ void prep_mats(const float* __restrict__ w3, v2f* __restrict__ mats) {
    int t = threadIdx.x;
    if (t < NLAYERS * NQ) {
        float phi = w3[t * 3 + 0], th = w3[t * 3 + 1], om = w3[t * 3 + 2];
        float ct = cosf(0.5f * th), s = sinf(0.5f * th);
        float ap = 0.5f * (phi + om), am = 0.5f * (phi - om);
        float cap = cosf(ap), sap = sinf(ap);
        float cam = cosf(am), sam = sinf(am);
        float2 m00 = make_float2( cap * ct, -sap * ct);
        float2 m01 = make_float2(-cam * s,  -sam * s);
        float2 m10 = make_float2( cam * s,  -sam * s);
        float2 m11 = make_float2( cap * ct,  sap * ct);
        v2f* M = mats + t * 8;
        M[0] = v2f{m00.x, m00.x};  M[1] = v2f{-m00.y, m00.y};
        M[2] = v2f{m01.x, m01.x};  M[3] = v2f{-m01.y, m01.y};
        M[4] = v2f{m10.x, m10.x};  M[5] = v2f{-m10.y, m10.y};
        M[6] = v2f{m11.x, m11.x};  M[7] = v2f{-m11.y, m11.y};
    }
}

__device__ __forceinline__ float wsum(float v) {
    v += lx<5>(v); v += lx<4>(v); v += lx<3>(v);
    v += lx<2>(v); v += lx<1>(v); v += lx<0>(v);
    return v;
}

// ================= main kernel =================
__global__ __launch_bounds__(256)
__attribute__((amdgpu_waves_per_eu(2, 4)))
void qsim_kernel(
    const float* __restrict__ x,       // [B][NQ]
    const v2f* __restrict__ mats,      // [NLAYERS][NQ][8] packed
    float* __restrict__ out)           // [B][NQ]
{
    __shared__ v2f xch[4096];          // 32 KB, k-order with phys() swizzle

    const int b     = blockIdx.x;
    const int tid   = threadIdx.x;
    const int wv    = tid >> 6;
    const int lane  = tid & 63;
    const int wbase = (wv << 10) | (lane << 4);
    const int lsw   = lane & 15;

    const float PI = 3.14159265358979323846f;

    // ---- RY on |0..0> is a PRODUCT STATE: amp(k) = prod_w (bit_w(k) ? sin_w : cos_w) ----
    float cs[12], sn[12];
    #pragma unroll
    for (int w = 0; w < 12; ++w) {
        float h = 0.5f * PI * x[b * NQ + w];
        __sincosf(h, &sn[w], &cs[w]);
    }
    float WF = (((wv >> 1) & 1) ? sn[0] : cs[0]) * ((wv & 1) ? sn[1] : cs[1]);
    #pragma unroll
    for (int W = 2; W < 8; ++W)
        WF *= ((lane >> (7 - W)) & 1) ? sn[W] : cs[W];

    v2f st[16];
    #pragma unroll
    for (int r = 0; r < 16; ++r) {
        float f = WF;
        f *= (r & 8) ? sn[8]  : cs[8];    // wire 8  <-> bit 3
        f *= (r & 4) ? sn[9]  : cs[9];    // wire 9  <-> bit 2
        f *= (r & 2) ? sn[10] : cs[10];   // wire 10 <-> bit 1
        f *= (r & 1) ? sn[11] : cs[11];   // wire 11 <-> bit 0
        st[r] = v2f{f, 0.f};
    }

    // ---- initial CNOT ring r=1 : one LDS permutation trip ----
    ring_trip<1>(st, wbase, lsw, xch);

    // ---- entangling layers ----
    #pragma unroll 1
    for (int l = 0; l < NLAYERS; ++l) {
        const v2f* M = mats + l * (NQ * 8);
        #define ROTW(W) rot_w<W>(st, wv, lane, wbase, lsw, xch, M + W * 8);
        ROTW(0) ROTW(1) ROTW(2) ROTW(3) ROTW(4) ROTW(5)
        ROTW(6) ROTW(7) ROTW(8) ROTW(9) ROTW(10) ROTW(11)
        #undef ROTW
        if      (l == 0) ring_trip<1>(st, wbase, lsw, xch);
        else if (l == 1) ring_trip<2>(st, wbase, lsw, xch);
        else if (l == 2) ring_trip<3>(st, wbase, lsw, xch);
        else             ring_trip<4>(st, wbase, lsw, xch);
    }

    // ---- per-wire <Z>, one wire at a time (low live-register pressure) ----
    float S = 0.f;
    float aR[4] = {0.f, 0.f, 0.f, 0.f};
    #pragma unroll
    for (int r = 0; r < 16; ++r) {
        v2f sq = st[r] * st[r];
        float pr = sq.x + sq.y;
        S += pr;
        #pragma unroll
        for (int rb = 0; rb < 4; ++rb)
            aR[rb] += ((r >> rb) & 1) ? -pr : pr;
    }

    float* red = (float*)xch;

    // wave wires 0,1: one shared butterfly, wave-dependent sign at write
    {
        float T = wsum(S);
        if (lane == 0) {
            red[wv * 12 + 0] = ((wv >> 1) & 1) ? -T : T;
            red[wv * 12 + 1] = (wv & 1) ? -T : T;
        }
    }
    // lane wires 2..7 (wire W -> lane bit 7-W)
    #pragma unroll
    for (int W = 2; W < 8; ++W) {
        float v0 = ((lane >> (7 - W)) & 1) ? -S : S;
        v0 = wsum(v0);
        if (lane == 0) red[wv * 12 + W] = v0;
    }
    // reg wires 8..11
    #pragma unroll
    for (int W = 8; W < 12; ++W) {
        float v0 = wsum(aR[11 - W]);
        if (lane == 0) red[wv * 12 + W] = v0;
    }
    __syncthreads();
    if (tid < 12)
        out[b * NQ + tid] = red[tid] + red[12 + tid] + red[24 + tid] + red[36 + tid];
}

extern "C" void kernel_launch(void* const* d_in, const int* in_sizes, int n_in,
                              void* d_out, int out_size, void* d_ws, size_t ws_size,
                              hipStream_t stream) {
    const float* x  = (const float*)d_in[0];   // [B][NQ] float32
    const float* w3 = (const float*)d_in[1];   // [NLAYERS][NQ][3] float32
    float* out = (float*)d_out;                // [B][NQ] float32
    v2f* mats = (v2f*)d_ws;                    // 48 * 8 * 8 B = 3 KB
    int batch = in_sizes[0] / NQ;
    prep_mats<<<1, 64, 0, stream>>>(w3, mats);
    qsim_kernel<<<batch, 256, 0, stream>>>(x, mats, out);
}